// Round 6
// baseline (150.048 us; speedup 1.0000x reference)
//
#include <hip/hip_runtime.h>

#define BIGF 1e30f
#define LOG2E 1.4426950408889634f
#define LN2F 0.6931471805599453f

constexpr int NB = 16;    // batches
constexpr int NN = 512;   // N rows
constexpr int MM = 512;   // M cols
constexpr int KD = 64;    // feature dim
constexpr int WAVES = 8;                     // 512 threads, 1 row/lane
constexpr int CSPAN = 32;                    // diagonals per barrier phase
constexpr int NSPANS = 32;                   // 1023 diagonals / 32
constexpr int SPW = 18;                      // spans per 64-row block
constexpr int TPH = 3 * (WAVES - 1) + SPW;   // 39 barrier phases
constexpr int DIAGELEMS = NN * MM;

constexpr int BBSTRIDE = MM + 2;                      // 514
constexpr int BUFD_FLOATS = WAVES * 2 * CSPAN * 64;   // 32768 (128 KiB)
constexpr int BBUF_FLOATS = WAVES * BBSTRIDE;         // 4112  (16 KiB)
constexpr int SMEM_BYTES = (BUFD_FLOATS + BBUF_FLOATS) * 4;  // 147520

// Packed anti-diagonal layout: element (i,j) [0-based] lives at
// Dsk[b*DIAGELEMS + B(s) + i],  s = i+j.
__device__ __forceinline__ int Bclosed(int s) {
  return (s <= 511) ? (s * (s + 1)) / 2
                    : DIAGELEMS - ((1023 - s) * (1024 - s)) / 2 - (s - 511);
}

// ---------------- Kernel 1: pairwise squared distances (exp2-domain) -------
// Computes 64x64 tile, stages in LDS, stores anti-diagonal-major with
// fully coalesced 64-lane segment stores.
__global__ __launch_bounds__(256) void pairdist_kernel(
    const float* __restrict__ X, const float* __restrict__ Y,
    float* __restrict__ Dsk) {
  const int b = blockIdx.z;
  const int i0 = blockIdx.y * 64;
  const int j0 = blockIdx.x * 64;

  __shared__ float Xs[64][65];
  __shared__ float Ys[64][65];
  __shared__ float Ds[64][66];  // stride 66: diag reads (stride 65) conflict-free

  const float* Xb = X + ((size_t)b * NN + i0) * KD;
  const float* Yb = Y + ((size_t)b * MM + j0) * KD;
  for (int k = threadIdx.x; k < 64 * KD; k += 256) {
    Xs[k >> 6][k & 63] = Xb[k];
    Ys[k >> 6][k & 63] = Yb[k];
  }
  __syncthreads();

  const int tx = threadIdx.x & 15;
  const int ty = threadIdx.x >> 4;
  const int r0 = ty * 4, c0 = tx * 4;

  float acc[4][4];
#pragma unroll
  for (int a = 0; a < 4; ++a)
#pragma unroll
    for (int e = 0; e < 4; ++e) acc[a][e] = 0.0f;

  for (int d = 0; d < KD; ++d) {
    float xv[4], yv[4];
#pragma unroll
    for (int q = 0; q < 4; ++q) xv[q] = Xs[r0 + q][d];
#pragma unroll
    for (int q = 0; q < 4; ++q) yv[q] = Ys[c0 + q][d];
#pragma unroll
    for (int a = 0; a < 4; ++a)
#pragma unroll
      for (int e = 0; e < 4; ++e) {
        float df = xv[a] - yv[e];
        acc[a][e] = fmaf(df, df, acc[a][e]);
      }
  }

#pragma unroll
  for (int a = 0; a < 4; ++a)
#pragma unroll
    for (int e = 0; e < 4; ++e)
      Ds[r0 + a][c0 + e] = fminf(acc[a][e], 10000.0f) * LOG2E;
  __syncthreads();

  // diag-major coalesced stores: wave handles diag sl, 64 lanes = 1 segment
  const int wv = threadIdx.x >> 6;
  const int ln = threadIdx.x & 63;
  float* Db = Dsk + (size_t)b * DIAGELEMS;
  for (int sl = wv; sl < 127; sl += 4) {
    const int istart = sl > 63 ? sl - 63 : 0;
    const int iend = sl < 63 ? sl : 63;
    if (ln <= iend - istart) {
      const int ig = i0 + istart + ln;  // global row
      Db[Bclosed(i0 + j0 + sl) + ig] = Ds[istart + ln][sl - istart - ln];
    }
  }
}

// DPP wave_shr:1 — lane i gets lane i-1's value; lane 0 gets `fill`.
__device__ __forceinline__ float dpp_shr1(float v, float fill) {
  return __int_as_float(__builtin_amdgcn_update_dpp(
      __float_as_int(fill), __float_as_int(v), 0x138 /*WAVE_SHR1*/, 0xf, 0xf,
      false));
}

// DMA one span's D-block (32 steps x 64 rows) for row-block blk into LDS.
// 8 x global_load_lds width-16: lane l covers step 4u+(l>>4),
// rows 64*blk + (l&15)*4 .. +3; LDS float index = 256u + 4*lane (linear).
__device__ __forceinline__ void dma_span(const float* __restrict__ Dskb,
                                         float* bufD, int blk, int q,
                                         int lane) {
  float* dst0 = bufD + (blk * 2 + (q & 1)) * (CSPAN * 64);
  const int rbase = 64 * blk + (lane & 15) * 4;
  const int sub = lane >> 4;
#pragma unroll
  for (int u = 0; u < 8; ++u) {
    int s = 32 * q + 4 * u + sub;
    s = s > 1022 ? 1022 : s;
    int e = Bclosed(s) + rbase;
    e = e > DIAGELEMS - 4 ? DIAGELEMS - 4 : e;  // junk rows masked later
    __builtin_amdgcn_global_load_lds(
        (const __attribute__((address_space(1))) void*)(Dskb + e),
        (__attribute__((address_space(3))) void*)(dst0 + u * 256), 16, 0, 0);
  }
}

// ---------------- Kernel 2: soft-DTW wavefront DP (base-2 domain) ----------
// One block per batch, 8 waves x 64 lanes, 1 row per lane (2 waves/SIMD).
// Row-block assignment blk = 2*(w&3)+(w>>2) so SIMD-sharing waves (w, w+4)
// own adjacent blocks -> overlapping active windows (stall filling).
// D values for all 32 steps are force-preloaded into 32 VGPRs via one
// mega-asm (32x ds_read_b32 + lgkmcnt(0)) so the step loop is pure VALU.
extern __shared__ float smem[];
__global__ __launch_bounds__(512) void softdtw_kernel(
    const float* __restrict__ Dsk, float* __restrict__ out) {
  const int b = blockIdx.x;
  const int t = threadIdx.x;
  const int wu = __builtin_amdgcn_readfirstlane(t >> 6);
  const int lane = t & 63;
  const int blk = ((wu & 3) << 1) | (wu >> 2);  // row-block 0..7

  float* bufD = smem;                // [8][2][32][64]
  float* bbuf = smem + BUFD_FLOATS;  // [8][514]: bbuf[k][j] = R'[64k][j]

  for (int k = t; k < BBUF_FLOATS; k += 512) bbuf[k] = BIGF;
  __syncthreads();

  const float* __restrict__ Dskb = Dsk + (size_t)b * DIAGELEMS;

  // pre-issue DMA for this block's first span (parity (2*blk)&1 == 0)
  dma_span(Dskb, bufD, blk, 2 * blk, lane);

  const int r = 64 * blk + lane;  // 0-based row; cell row i = r+1
  float ra = BIGF;                // R'[i][j-1]
  // up2 source: previous step's up1 (= R'[i-1][j-1]).  Seed: R'[i-1][0],
  // which is R'[0][0]=0 only for the global first row's lane.
  float up1p = (blk == 0 && lane == 0) ? 0.0f : BIGF;

  for (int S = 0; S < TPH; ++S) {
    const int cc = S - 3 * blk;  // phase-local span index
    if (cc >= 0 && cc < SPW) {
      const int c = cc + 2 * blk;  // global span (<= 31)
      const bool issue = (cc + 1 < SPW);
      if (issue) {
        dma_span(Dskb, bufD, blk, c + 1, lane);
        asm volatile("s_waitcnt vmcnt(8)" ::: "memory");  // span-c DMA done
      } else {
        asm volatile("s_waitcnt vmcnt(0)" ::: "memory");
      }

      // boundary row segment; only lanes 0..31 consumed via readlane
      int bi = 32 * cc + 1 + (lane & 31);
      bi = bi > 513 ? 513 : bi;
      const float browA = blk ? bbuf[blk * BBSTRIDE + bi] : BIGF;

      const float* myD = bufD + (blk * 2 + (c & 1)) * (CSPAN * 64);
      const __attribute__((address_space(3))) float* mp =
          (const __attribute__((address_space(3))) float*)(myD + lane);
      unsigned maddr = (unsigned)(size_t)mp;

      float dv[CSPAN];
      asm volatile(
          "ds_read_b32 %0, %32 offset:0\n\t"
          "ds_read_b32 %1, %32 offset:256\n\t"
          "ds_read_b32 %2, %32 offset:512\n\t"
          "ds_read_b32 %3, %32 offset:768\n\t"
          "ds_read_b32 %4, %32 offset:1024\n\t"
          "ds_read_b32 %5, %32 offset:1280\n\t"
          "ds_read_b32 %6, %32 offset:1536\n\t"
          "ds_read_b32 %7, %32 offset:1792\n\t"
          "ds_read_b32 %8, %32 offset:2048\n\t"
          "ds_read_b32 %9, %32 offset:2304\n\t"
          "ds_read_b32 %10, %32 offset:2560\n\t"
          "ds_read_b32 %11, %32 offset:2816\n\t"
          "ds_read_b32 %12, %32 offset:3072\n\t"
          "ds_read_b32 %13, %32 offset:3328\n\t"
          "ds_read_b32 %14, %32 offset:3584\n\t"
          "ds_read_b32 %15, %32 offset:3840\n\t"
          "ds_read_b32 %16, %32 offset:4096\n\t"
          "ds_read_b32 %17, %32 offset:4352\n\t"
          "ds_read_b32 %18, %32 offset:4608\n\t"
          "ds_read_b32 %19, %32 offset:4864\n\t"
          "ds_read_b32 %20, %32 offset:5120\n\t"
          "ds_read_b32 %21, %32 offset:5376\n\t"
          "ds_read_b32 %22, %32 offset:5632\n\t"
          "ds_read_b32 %23, %32 offset:5888\n\t"
          "ds_read_b32 %24, %32 offset:6144\n\t"
          "ds_read_b32 %25, %32 offset:6400\n\t"
          "ds_read_b32 %26, %32 offset:6656\n\t"
          "ds_read_b32 %27, %32 offset:6912\n\t"
          "ds_read_b32 %28, %32 offset:7168\n\t"
          "ds_read_b32 %29, %32 offset:7424\n\t"
          "ds_read_b32 %30, %32 offset:7680\n\t"
          "ds_read_b32 %31, %32 offset:7936\n\t"
          "s_waitcnt lgkmcnt(0)"
          : "=&v"(dv[0]), "=&v"(dv[1]), "=&v"(dv[2]), "=&v"(dv[3]),
            "=&v"(dv[4]), "=&v"(dv[5]), "=&v"(dv[6]), "=&v"(dv[7]),
            "=&v"(dv[8]), "=&v"(dv[9]), "=&v"(dv[10]), "=&v"(dv[11]),
            "=&v"(dv[12]), "=&v"(dv[13]), "=&v"(dv[14]), "=&v"(dv[15]),
            "=&v"(dv[16]), "=&v"(dv[17]), "=&v"(dv[18]), "=&v"(dv[19]),
            "=&v"(dv[20]), "=&v"(dv[21]), "=&v"(dv[22]), "=&v"(dv[23]),
            "=&v"(dv[24]), "=&v"(dv[25]), "=&v"(dv[26]), "=&v"(dv[27]),
            "=&v"(dv[28]), "=&v"(dv[29]), "=&v"(dv[30]), "=&v"(dv[31])
          : "v"(maddr)
          : "memory");

      const int jv0 = 32 * c - r + 1;  // column j at k=0
#pragma unroll
      for (int k = 0; k < CSPAN; ++k) {
        const float o1 = __int_as_float(
            __builtin_amdgcn_readlane(__float_as_int(browA), k));
        const float up1 = dpp_shr1(ra, o1);  // R'[i-1][j]
        const float up2 = up1p;              // R'[i-1][j-1]
        up1p = up1;

        const float m = fminf(fminf(up1, up2), ra);
        const float md = __builtin_amdgcn_fmed3f(up1, up2, ra);
        const float mx = fmaxf(fmaxf(up1, up2), ra);
        const float ssum = 1.0f + __builtin_amdgcn_exp2f(m - md) +
                           __builtin_amdgcn_exp2f(m - mx);
        const float n = dv[k] + (m - __builtin_amdgcn_logf(ssum));

        const int jv = jv0 + k;
        const bool a0 = (unsigned)(jv - 1) < (unsigned)MM;
        ra = a0 ? n : ra;

        // publish boundary row for next block (row 64(blk+1) = lane63's row)
        if (blk < WAVES - 1 && lane == 63 && a0)
          bbuf[(blk + 1) * BBSTRIDE + jv] = n;
      }
    }
    __syncthreads();
  }

  if (blk == WAVES - 1 && lane == 63) out[b] = ra * LN2F;  // R'[512][512]
}

extern "C" void kernel_launch(void* const* d_in, const int* in_sizes, int n_in,
                              void* d_out, int out_size, void* d_ws,
                              size_t ws_size, hipStream_t stream) {
  const float* X = (const float*)d_in[0];
  const float* Y = (const float*)d_in[1];
  float* out = (float*)d_out;
  float* Dsk = (float*)d_ws;

  const size_t needed = (size_t)NB * DIAGELEMS * sizeof(float);
  if (ws_size < needed) return;

  hipFuncSetAttribute((const void*)softdtw_kernel,
                      hipFuncAttributeMaxDynamicSharedMemorySize, SMEM_BYTES);

  pairdist_kernel<<<dim3(MM / 64, NN / 64, NB), 256, 0, stream>>>(X, Y, Dsk);
  softdtw_kernel<<<NB, 512, SMEM_BYTES, stream>>>(Dsk, out);
}

// Round 7
// 132.262 us; speedup vs baseline: 1.1345x; 1.1345x over previous
//
#include <hip/hip_runtime.h>

#define BIGF 1e30f
#define LOG2E 1.4426950408889634f
#define LN2F 0.6931471805599453f

constexpr int NB = 16;    // batches
constexpr int NN = 512;   // N rows
constexpr int MM = 512;   // M cols
constexpr int KD = 64;    // feature dim
constexpr int WAVES = 8;                     // 512 threads, 1 row/lane
constexpr int CSPAN = 32;                    // diagonals per barrier phase
constexpr int NSPANS = 32;                   // 1023 diagonals / 32
constexpr int SPW = 18;                      // spans per 64-row block
constexpr int TPH = 3 * (WAVES - 1) + SPW;   // 39 barrier phases
constexpr int DIAGELEMS = NN * MM;

// bbuf row covers columns [-62, 609] -> index = 62 + j, stride 672.
constexpr int BBSTRIDE = 672;
constexpr int BUFD_FLOATS = WAVES * 2 * CSPAN * 64;   // 32768 (128 KiB)
constexpr int BBUF_FLOATS = WAVES * BBSTRIDE;         // 5376  (21 KiB)
constexpr int SMEM_BYTES = (BUFD_FLOATS + BBUF_FLOATS) * 4;  // 152576

// Packed anti-diagonal layout: element (i,j) [0-based] lives at
// Dsk[b*DIAGELEMS + B(s) + i],  s = i+j.
__device__ __forceinline__ int Bclosed(int s) {
  return (s <= 511) ? (s * (s + 1)) / 2
                    : DIAGELEMS - ((1023 - s) * (1024 - s)) / 2 - (s - 511);
}

// ---------------- Kernel 1: pairwise squared distances (exp2-domain) -------
__global__ __launch_bounds__(256) void pairdist_kernel(
    const float* __restrict__ X, const float* __restrict__ Y,
    float* __restrict__ Dsk) {
  const int b = blockIdx.z;
  const int i0 = blockIdx.y * 64;
  const int j0 = blockIdx.x * 64;

  __shared__ float Xs[64][65];
  __shared__ float Ys[64][65];
  __shared__ float Ds[64][66];  // stride 66: diag reads (stride 65) conflict-free

  const float* Xb = X + ((size_t)b * NN + i0) * KD;
  const float* Yb = Y + ((size_t)b * MM + j0) * KD;
  for (int k = threadIdx.x; k < 64 * KD; k += 256) {
    Xs[k >> 6][k & 63] = Xb[k];
    Ys[k >> 6][k & 63] = Yb[k];
  }
  __syncthreads();

  const int tx = threadIdx.x & 15;
  const int ty = threadIdx.x >> 4;
  const int r0 = ty * 4, c0 = tx * 4;

  float acc[4][4];
#pragma unroll
  for (int a = 0; a < 4; ++a)
#pragma unroll
    for (int e = 0; e < 4; ++e) acc[a][e] = 0.0f;

  for (int d = 0; d < KD; ++d) {
    float xv[4], yv[4];
#pragma unroll
    for (int q = 0; q < 4; ++q) xv[q] = Xs[r0 + q][d];
#pragma unroll
    for (int q = 0; q < 4; ++q) yv[q] = Ys[c0 + q][d];
#pragma unroll
    for (int a = 0; a < 4; ++a)
#pragma unroll
      for (int e = 0; e < 4; ++e) {
        float df = xv[a] - yv[e];
        acc[a][e] = fmaf(df, df, acc[a][e]);
      }
  }

#pragma unroll
  for (int a = 0; a < 4; ++a)
#pragma unroll
    for (int e = 0; e < 4; ++e)
      Ds[r0 + a][c0 + e] = fminf(acc[a][e], 10000.0f) * LOG2E;
  __syncthreads();

  // diag-major coalesced stores: wave handles diag sl, 64 lanes = 1 segment
  const int wv = threadIdx.x >> 6;
  const int ln = threadIdx.x & 63;
  float* Db = Dsk + (size_t)b * DIAGELEMS;
  for (int sl = wv; sl < 127; sl += 4) {
    const int istart = sl > 63 ? sl - 63 : 0;
    const int iend = sl < 63 ? sl : 63;
    if (ln <= iend - istart) {
      const int ig = i0 + istart + ln;  // global row
      Db[Bclosed(i0 + j0 + sl) + ig] = Ds[istart + ln][sl - istart - ln];
    }
  }
}

// up1 = lane i-1's ra; lane 0 takes old[lane0] = B[lane0] (boundary inject).
__device__ __forceinline__ float dpp_shr1_old(float oldv, float v) {
  return __int_as_float(__builtin_amdgcn_update_dpp(
      __float_as_int(oldv), __float_as_int(v), 0x138 /*WAVE_SHR1*/, 0xf, 0xf,
      false));
}
// B[l] <- B[l+1] (advance boundary stream; high lanes keep junk).
__device__ __forceinline__ float dpp_shl1(float v) {
  return __int_as_float(__builtin_amdgcn_update_dpp(
      __float_as_int(v), __float_as_int(v), 0x130 /*WAVE_SHL1*/, 0xf, 0xf,
      false));
}

// DMA one span's D-block (32 steps x 64 rows) for row-block blk into LDS.
__device__ __forceinline__ void dma_span(const float* __restrict__ Dskb,
                                         float* bufD, int blk, int q,
                                         int lane) {
  float* dst0 = bufD + (blk * 2 + (q & 1)) * (CSPAN * 64);
  const int rbase = 64 * blk + (lane & 15) * 4;
  const int sub = lane >> 4;
#pragma unroll
  for (int u = 0; u < 8; ++u) {
    int s = 32 * q + 4 * u + sub;
    s = s > 1022 ? 1022 : s;
    int e = Bclosed(s) + rbase;
    e = e > DIAGELEMS - 4 ? DIAGELEMS - 4 : e;  // junk rows masked later
    __builtin_amdgcn_global_load_lds(
        (const __attribute__((address_space(1))) void*)(Dskb + e),
        (__attribute__((address_space(3))) void*)(dst0 + u * 256), 16, 0, 0);
  }
}

#define SOFTMIN_STEP(K)                                                     \
  {                                                                         \
    const float up1 = dpp_shr1_old(B, ra);                                  \
    B = dpp_shl1(B);                                                        \
    const float m = fminf(fminf(up1, up2), ra);                             \
    const float md = __builtin_amdgcn_fmed3f(up1, up2, ra);                 \
    const float mx = fmaxf(fmaxf(up1, up2), ra);                            \
    const float ssum = (__builtin_amdgcn_exp2f(m - md) +                    \
                        __builtin_amdgcn_exp2f(m - mx)) +                   \
                       1.0f;                                                \
    n = dv[K] + (m - __builtin_amdgcn_logf(ssum));                          \
    up2 = up1;                                                              \
  }

// ---------------- Kernel 2: soft-DTW wavefront DP (base-2 domain) ----------
// One block per batch, 8 waves x 64 lanes, 1 row per lane (2 waves/SIMD).
// Fast phases (all lanes active): 15-instr step — dpp, min3/med3/max3,
// 2 exp2, log2, adds, 1 unmasked ds_write publish. Boundary values stream
// through a DPP-shifting register; no readlane, no exec masking.
extern __shared__ float smem[];
__global__ __launch_bounds__(512) void softdtw_kernel(
    const float* __restrict__ Dsk, float* __restrict__ out) {
  const int b = blockIdx.x;
  const int t = threadIdx.x;
  const int wu = __builtin_amdgcn_readfirstlane(t >> 6);
  const int lane = t & 63;
  const int blk = ((wu & 3) << 1) | (wu >> 2);  // row-block 0..7

  float* bufD = smem;                // [8][2][32][64]
  float* bbuf = smem + BUFD_FLOATS;  // [8][672]: row w col j at [w][62+j]

  for (int k = t; k < BBUF_FLOATS; k += 512) bbuf[k] = BIGF;
  __syncthreads();

  const float* __restrict__ Dskb = Dsk + (size_t)b * DIAGELEMS;

  // pre-issue DMA for this block's first span (parity (2*blk)&1 == 0)
  dma_span(Dskb, bufD, blk, 2 * blk, lane);

  const int r = 64 * blk + lane;  // 0-based row; cell row i = r+1
  float ra = BIGF;                // R'[i][j-1]
  // up2 = R'[i-1][j-1] = previous step's up1; seed R'[0][0]=0 for the origin.
  float up2 = (blk == 0 && lane == 0) ? 0.0f : BIGF;

  for (int S = 0; S < TPH; ++S) {
    const int cc = S - 3 * blk;  // phase-local span index
    if (cc >= 0 && cc < SPW) {
      const int c = cc + 2 * blk;  // global span (<= 31)
      if (cc + 1 < SPW) {
        dma_span(Dskb, bufD, blk, c + 1, lane);
        asm volatile("s_waitcnt vmcnt(8)" ::: "memory");  // span-c DMA done
      } else {
        asm volatile("s_waitcnt vmcnt(0)" ::: "memory");
      }

      // boundary stream: B[lane] = R'[64blk][32cc+1+lane]; step k consumes
      // B-orig[k] (k<=31) via lane0 of the dpp old-operand.
      float B = BIGF;
      if (blk) B = bbuf[blk * BBSTRIDE + 62 + 32 * cc + 1 + lane];

      const float* myD = bufD + (blk * 2 + (c & 1)) * (CSPAN * 64);
      const __attribute__((address_space(3))) float* mp =
          (const __attribute__((address_space(3))) float*)(myD + lane);
      unsigned maddr = (unsigned)(size_t)mp;

      float dv[CSPAN];
      asm volatile(
          "ds_read_b32 %0, %32 offset:0\n\t"
          "ds_read_b32 %1, %32 offset:256\n\t"
          "ds_read_b32 %2, %32 offset:512\n\t"
          "ds_read_b32 %3, %32 offset:768\n\t"
          "ds_read_b32 %4, %32 offset:1024\n\t"
          "ds_read_b32 %5, %32 offset:1280\n\t"
          "ds_read_b32 %6, %32 offset:1536\n\t"
          "ds_read_b32 %7, %32 offset:1792\n\t"
          "ds_read_b32 %8, %32 offset:2048\n\t"
          "ds_read_b32 %9, %32 offset:2304\n\t"
          "ds_read_b32 %10, %32 offset:2560\n\t"
          "ds_read_b32 %11, %32 offset:2816\n\t"
          "ds_read_b32 %12, %32 offset:3072\n\t"
          "ds_read_b32 %13, %32 offset:3328\n\t"
          "ds_read_b32 %14, %32 offset:3584\n\t"
          "ds_read_b32 %15, %32 offset:3840\n\t"
          "ds_read_b32 %16, %32 offset:4096\n\t"
          "ds_read_b32 %17, %32 offset:4352\n\t"
          "ds_read_b32 %18, %32 offset:4608\n\t"
          "ds_read_b32 %19, %32 offset:4864\n\t"
          "ds_read_b32 %20, %32 offset:5120\n\t"
          "ds_read_b32 %21, %32 offset:5376\n\t"
          "ds_read_b32 %22, %32 offset:5632\n\t"
          "ds_read_b32 %23, %32 offset:5888\n\t"
          "ds_read_b32 %24, %32 offset:6144\n\t"
          "ds_read_b32 %25, %32 offset:6400\n\t"
          "ds_read_b32 %26, %32 offset:6656\n\t"
          "ds_read_b32 %27, %32 offset:6912\n\t"
          "ds_read_b32 %28, %32 offset:7168\n\t"
          "ds_read_b32 %29, %32 offset:7424\n\t"
          "ds_read_b32 %30, %32 offset:7680\n\t"
          "ds_read_b32 %31, %32 offset:7936\n\t"
          "s_waitcnt lgkmcnt(0)"
          : "=&v"(dv[0]), "=&v"(dv[1]), "=&v"(dv[2]), "=&v"(dv[3]),
            "=&v"(dv[4]), "=&v"(dv[5]), "=&v"(dv[6]), "=&v"(dv[7]),
            "=&v"(dv[8]), "=&v"(dv[9]), "=&v"(dv[10]), "=&v"(dv[11]),
            "=&v"(dv[12]), "=&v"(dv[13]), "=&v"(dv[14]), "=&v"(dv[15]),
            "=&v"(dv[16]), "=&v"(dv[17]), "=&v"(dv[18]), "=&v"(dv[19]),
            "=&v"(dv[20]), "=&v"(dv[21]), "=&v"(dv[22]), "=&v"(dv[23]),
            "=&v"(dv[24]), "=&v"(dv[25]), "=&v"(dv[26]), "=&v"(dv[27]),
            "=&v"(dv[28]), "=&v"(dv[29]), "=&v"(dv[30]), "=&v"(dv[31])
          : "v"(maddr)
          : "memory");

      // unmasked publish target: column jv(k) = 32c - r + 1 + k.
      // Lane 63 (the true boundary row 64(blk+1)) is provably the LAST
      // writer of every column the next block consumes; blk 7 dumps to
      // row 0 (never read).
      float* pubp =
          bbuf + ((blk + 1) & 7) * BBSTRIDE + (62 + 32 * c - r + 1);

      float n;
      if (cc >= 2 && cc <= 15) {  // all 64 lanes active at all 32 steps
#pragma unroll
        for (int k = 0; k < CSPAN; ++k) {
          SOFTMIN_STEP(k);
          ra = n;
          pubp[k] = ra;
        }
      } else {  // edge phases: keep activity mask
        const int jv0 = 32 * c - r + 1;
#pragma unroll
        for (int k = 0; k < CSPAN; ++k) {
          SOFTMIN_STEP(k);
          const bool a0 = (unsigned)(jv0 + k - 1) < (unsigned)MM;
          ra = a0 ? n : ra;
          pubp[k] = ra;
        }
      }
    }
    __syncthreads();
  }

  if (blk == WAVES - 1 && lane == 63) out[b] = ra * LN2F;  // R'[512][512]
}

extern "C" void kernel_launch(void* const* d_in, const int* in_sizes, int n_in,
                              void* d_out, int out_size, void* d_ws,
                              size_t ws_size, hipStream_t stream) {
  const float* X = (const float*)d_in[0];
  const float* Y = (const float*)d_in[1];
  float* out = (float*)d_out;
  float* Dsk = (float*)d_ws;

  const size_t needed = (size_t)NB * DIAGELEMS * sizeof(float);
  if (ws_size < needed) return;

  hipFuncSetAttribute((const void*)softdtw_kernel,
                      hipFuncAttributeMaxDynamicSharedMemorySize, SMEM_BYTES);

  pairdist_kernel<<<dim3(MM / 64, NN / 64, NB), 256, 0, stream>>>(X, Y, Dsk);
  softdtw_kernel<<<NB, 512, SMEM_BYTES, stream>>>(Dsk, out);
}